// Round 11
// baseline (178.232 us; speedup 1.0000x reference)
//
#include <hip/hip_runtime.h>
#include <hip/hip_fp16.h>
#include <math.h>

#define NN 100000
#define NE 1600000

#define BSH  8          // bucket = dst >> 8
#define BKN  256        // nodes per bucket
#define NB2  391        // ceil(NN/256)
#define ABLK 256        // partition blocks
#define EPB  ((NE + ABLK - 1) / ABLK)   // 6250 edges per partition block
#define CAP  8192       // LDS cols capacity per bucket (expected ~4082, 64-sigma margin)

typedef __attribute__((ext_vector_type(8))) short bf16x8;
typedef __attribute__((ext_vector_type(4))) float f32x4;

__device__ __forceinline__ unsigned short f2bf(float f) {
    unsigned u = __builtin_bit_cast(unsigned, f);
    u += 0x7fffu + ((u >> 16) & 1u);           // RNE
    return (unsigned short)(u >> 16);
}
__device__ __forceinline__ float bf2f(unsigned short h) {
    unsigned u = ((unsigned)h) << 16;
    return __builtin_bit_cast(float, u);
}
__device__ __forceinline__ float2 unpackh2(unsigned w) {
    const __half2 h = __builtin_bit_cast(__half2, w);
    return __half22float2(h);
}

// ---- fused precomp: blocks 0..127 -> ATh/ATl row k (transposed bf16 hi/lo of A);
//      block 128 -> cbuf [0:16)=b1@w2l [16:32)=b1@w2r [32:48)=fc1w@fc2w [48]=c
__global__ __launch_bounds__(64) void precomp(const float* __restrict__ w1l,
    const float* __restrict__ w1r, const float* __restrict__ w2l,
    const float* __restrict__ w2r, const float* __restrict__ b1,
    const float* __restrict__ fc1w, const float* __restrict__ fc1b,
    const float* __restrict__ fc2w, const float* __restrict__ fc2b,
    unsigned short* __restrict__ ATh, unsigned short* __restrict__ ATl,
    float* __restrict__ cbuf)
{
    const int j = threadIdx.x;
    if (blockIdx.x == 128) {
        if (j < 16) {
            float a = 0.f;
            for (int m = 0; m < 64; ++m) a = fmaf(b1[m], w2l[m * 16 + j], a);
            cbuf[j] = a;
        } else if (j < 32) {
            const int jj = j - 16;
            float a = 0.f;
            for (int m = 0; m < 64; ++m) a = fmaf(b1[m], w2r[m * 16 + jj], a);
            cbuf[j] = a;
        } else if (j < 48) {
            const int k = j - 32;
            float a = 0.f;
            for (int m = 0; m < 8; ++m) a = fmaf(fc1w[k * 8 + m], fc2w[m], a);
            cbuf[j] = a;
        } else if (j == 48) {
            float a = fc2b[0];
            for (int m = 0; m < 8; ++m) a = fmaf(fc1b[m], fc2w[m], a);
            cbuf[48] = a;
        }
        return;
    }
    __shared__ float sl[64], sr[64];
    const int k = blockIdx.x;     // input feature 0..127
    sl[j] = w1l[k * 64 + j];
    sr[j] = w1r[k * 64 + j];
    __syncthreads();
    const int sel = j >> 4, jj = j & 15;
    const float* row = (sel < 2) ? sl : sr;
    const float* w2  = (sel & 1) ? w2r : w2l;
    float acc = 0.f;
#pragma unroll
    for (int m = 0; m < 64; ++m) acc = fmaf(row[m], w2[m * 16 + jj], acc);
    const unsigned short h = f2bf(acc);
    ATh[j * 128 + k] = h;                       // transposed: [col][k]
    ATl[j * 128 + k] = f2bf(acc - bf2f(h));
}

// ---- MFMA GEMM: y = x @ A (bf16 3-term split).
//      p (cols 0..31) -> int8 + per-row scale;  q (cols 32..63) -> fp16
#define LDST 136
__global__ __launch_bounds__(256) void gemm_mfma(const float* __restrict__ x,
    const unsigned short* __restrict__ ATh, const unsigned short* __restrict__ ATl,
    signed char* __restrict__ p8, float* __restrict__ pscale,
    __half* __restrict__ qh)
{
    __shared__ unsigned short sAh[64 * LDST];
    __shared__ unsigned short sAl[64 * LDST];
    const int tid = threadIdx.x;
    for (int i = tid; i < 1024; i += 256) {
        const int row = i >> 4, ch = i & 15;
        const uint4 vh = *(const uint4*)(ATh + row * 128 + ch * 8);
        const uint4 vl = *(const uint4*)(ATl + row * 128 + ch * 8);
        *(uint4*)(sAh + row * LDST + ch * 8) = vh;
        *(uint4*)(sAl + row * LDST + ch * 8) = vl;
    }
    __syncthreads();

    const int wave = tid >> 6;
    const int lane = tid & 63;
    const int lr = lane & 15;
    const int lg = lane >> 4;

    bf16x8 bh[4][4], bl[4][4];
#pragma unroll
    for (int ct = 0; ct < 4; ++ct) {
        const int col = ct * 16 + lr;
#pragma unroll
        for (int ks = 0; ks < 4; ++ks) {
            const int k0 = ks * 32 + lg * 8;
            bh[ct][ks] = *(const bf16x8*)(sAh + col * LDST + k0);
            bl[ct][ks] = *(const bf16x8*)(sAl + col * LDST + k0);
        }
    }

    const int tilebase = blockIdx.x * 64;
    const int xrowidx = tilebase + wave * 16 + lr;
    const float* xrow = x + (size_t)(xrowidx < NN ? xrowidx : NN - 1) * 128;

    f32x4 acc[4] = {f32x4{0,0,0,0}, f32x4{0,0,0,0}, f32x4{0,0,0,0}, f32x4{0,0,0,0}};
#pragma unroll
    for (int ks = 0; ks < 4; ++ks) {
        const int k0 = ks * 32 + lg * 8;
        const float4 v0 = *(const float4*)(xrow + k0);
        const float4 v1 = *(const float4*)(xrow + k0 + 4);
        const float vv[8] = {v0.x, v0.y, v0.z, v0.w, v1.x, v1.y, v1.z, v1.w};
        bf16x8 xh, xl;
#pragma unroll
        for (int j = 0; j < 8; ++j) {
            const unsigned short h = f2bf(vv[j]);
            xh[j] = (short)h;
            xl[j] = (short)f2bf(vv[j] - bf2f(h));
        }
#pragma unroll
        for (int ct = 0; ct < 4; ++ct) {
            acc[ct] = __builtin_amdgcn_mfma_f32_16x16x32_bf16(xh, bh[ct][ks], acc[ct], 0, 0, 0);
            acc[ct] = __builtin_amdgcn_mfma_f32_16x16x32_bf16(xh, bl[ct][ks], acc[ct], 0, 0, 0);
            acc[ct] = __builtin_amdgcn_mfma_f32_16x16x32_bf16(xl, bh[ct][ks], acc[ct], 0, 0, 0);
        }
    }

#pragma unroll
    for (int rg = 0; rg < 4; ++rg) {
        float m = fmaxf(fabsf(acc[0][rg]), fabsf(acc[1][rg]));
#pragma unroll
        for (int d = 1; d < 16; d <<= 1) m = fmaxf(m, __shfl_xor(m, d, 64));
        m = fmaxf(m, 1e-20f);
        const float scl = m * (1.0f / 127.0f);
        const float inv = 127.0f / m;
        const int nrow = tilebase + wave * 16 + lg * 4 + rg;
        if (nrow < NN) {
            const int q0 = __float2int_rn(acc[0][rg] * inv);
            const int q1 = __float2int_rn(acc[1][rg] * inv);
            p8[(size_t)nrow * 32 + lr]      = (signed char)q0;
            p8[(size_t)nrow * 32 + 16 + lr] = (signed char)q1;
            if (lr == 0) pscale[nrow] = scl;
            qh[(size_t)nrow * 32 + lr]      = __float2half(acc[2][rg]);
            qh[(size_t)nrow * 32 + 16 + lr] = __float2half(acc[3][rg]);
        }
    }
}

// ============ bucket partition ============
// mat layout: [bucket][ablock]
__global__ __launch_bounds__(256) void partA_count(const int* __restrict__ dst,
    int* __restrict__ mat)
{
    __shared__ int h[NB2];
    for (int i = threadIdx.x; i < NB2; i += 256) h[i] = 0;
    __syncthreads();
    const int a = blockIdx.x;
    const int beg = a * EPB;
    const int end = (beg + EPB < NE) ? beg + EPB : NE;
    for (int e = beg + threadIdx.x; e < end; e += 256)
        atomicAdd(&h[dst[e] >> BSH], 1);
    __syncthreads();
    for (int i = threadIdx.x; i < NB2; i += 256) mat[(size_t)i * ABLK + a] = h[i];
}

// single-block scan: per-bucket prefix over ABLK entries + bucket bases
__global__ __launch_bounds__(512) void scan_all(int* __restrict__ mat,
    int* __restrict__ bbase)
{
    __shared__ int s[512];
    const int t = threadIdx.x;
    int run = 0;
    if (t < NB2) {
        int* col = mat + (size_t)t * ABLK;
        for (int a = 0; a < ABLK; ++a) { const int v = col[a]; col[a] = run; run += v; }
    }
    s[t] = (t < NB2) ? run : 0;
    __syncthreads();
    for (int off = 1; off < 512; off <<= 1) {
        const int u = (t >= off) ? s[t - off] : 0;
        __syncthreads();
        s[t] += u;
        __syncthreads();
    }
    if (t < NB2) bbase[t] = s[t] - run;            // exclusive
    if (t == NB2 - 1) bbase[NB2] = s[t];           // == NE
}

// packed entry: (src << BSH) | local_dst
__global__ __launch_bounds__(256) void partA_scatter(const int* __restrict__ src,
    const int* __restrict__ dst, const int* __restrict__ mat,
    const int* __restrict__ bbase, unsigned* __restrict__ part)
{
    __shared__ int cur[NB2];
    const int a = blockIdx.x;
    for (int i = threadIdx.x; i < NB2; i += 256)
        cur[i] = mat[(size_t)i * ABLK + a] + bbase[i];
    __syncthreads();
    const int beg = a * EPB;
    const int end = (beg + EPB < NE) ? beg + EPB : NE;
    for (int e = beg + threadIdx.x; e < end; e += 256) {
        const int s = src[e], d = dst[e];
        const int pos = atomicAdd(&cur[d >> BSH], 1);
        part[pos] = ((unsigned)s << BSH) | (unsigned)(d & (BKN - 1));
    }
}

// ============ fused CSR-build + layer-1 aggregation ============
// One block per bucket: LDS histogram + scan + scatter (cols cached in LDS,
// also written to global for agg2), then vectorized gather-aggregate.
__global__ __launch_bounds__(512) void buildagg1(const unsigned* __restrict__ part,
    const int* __restrict__ bbase, const signed char* __restrict__ p8,
    const float* __restrict__ pscale, const __half* __restrict__ qh,
    const float* __restrict__ cbuf, int* __restrict__ rowptr,
    int* __restrict__ cols, __half* __restrict__ g, __half* __restrict__ r)
{
    __shared__ int cols_l[CAP];
    __shared__ int hist[BKN];
    __shared__ int lrow[BKN];
    __shared__ int cur[BKN];
    const int b = blockIdx.x;
    const int t = threadIdx.x;
    const int beg = bbase[b], end = bbase[b + 1];
    const int cnt = end - beg;

    if (t < BKN) hist[t] = 0;
    __syncthreads();
    for (int e = beg + t; e < end; e += 512)
        atomicAdd(&hist[part[e] & (BKN - 1u)], 1);
    __syncthreads();
    const int v = (t < BKN) ? hist[t] : 0;
    for (int off = 1; off < BKN; off <<= 1) {
        const int u = (t < BKN && t >= off) ? hist[t - off] : 0;
        __syncthreads();
        if (t < BKN) hist[t] += u;
        __syncthreads();
    }
    if (t < BKN) {
        const int excl = hist[t] - v;
        lrow[t] = excl;
        cur[t] = excl;
        const int node = (b << BSH) + t;
        if (node < NN) rowptr[node] = beg + excl;
    }
    if (b == NB2 - 1 && t == 0) rowptr[NN] = NE;
    __syncthreads();
    for (int e = beg + t; e < end; e += 512) {
        const unsigned w = part[e];
        const int pos = atomicAdd(&cur[w & (BKN - 1u)], 1);
        const int s = (int)(w >> BSH);
        cols[beg + pos] = s;
        if (pos < CAP) cols_l[pos] = s;
    }
    __syncthreads();

    // aggregation: 16 groups x 32 lanes; 4 edge-slots x 8 dword-lanes per group
    const int gi = t >> 5;
    const int lane = t & 31;
    const int es = lane >> 3;
    const int k = lane & 7;
    const unsigned* p32 = (const unsigned*)p8;
    for (int nd = gi; nd < BKN; nd += 16) {
        const int node = (b << BSH) + nd;
        if (node >= NN) continue;
        const int ls = lrow[nd];
        const int le = (nd == BKN - 1) ? cnt : lrow[nd + 1];
        float a0 = 0.f, a1 = 0.f, a2 = 0.f, a3 = 0.f;
#pragma unroll 2
        for (int j = ls; j < le; j += 4) {
            const int jj = j + es;
            const int idx = (jj < le) ? jj : le - 1;
            const int s = (idx < CAP) ? cols_l[idx] : cols[beg + idx];
            const float scl = (jj < le) ? pscale[s] : 0.f;
            const unsigned w = p32[(size_t)s * 8 + k];
            a0 = fmaf((float)(signed char)(w & 0xffu), scl, a0);
            a1 = fmaf((float)(signed char)((w >> 8) & 0xffu), scl, a1);
            a2 = fmaf((float)(signed char)((w >> 16) & 0xffu), scl, a2);
            a3 = fmaf((float)(signed char)(w >> 24), scl, a3);
        }
        a0 += __shfl_xor(a0, 8, 64);  a0 += __shfl_xor(a0, 16, 64);
        a1 += __shfl_xor(a1, 8, 64);  a1 += __shfl_xor(a1, 16, 64);
        a2 += __shfl_xor(a2, 8, 64);  a2 += __shfl_xor(a2, 16, 64);
        a3 += __shfl_xor(a3, 8, 64);  a3 += __shfl_xor(a3, 16, 64);
        if (es == 0) {
            const float dg = (float)(le - ls);
            const float inv = 1.0f / fmaxf(dg, 1.0f);
            const uint2 qw = *(const uint2*)(qh + (size_t)node * 32 + 4 * k);
            const float2 q01 = unpackh2(qw.x), q23 = unpackh2(qw.y);
            const float4 cb = *(const float4*)(cbuf + 4 * k);
            const float v0 = fmaf(a0, inv, q01.x + cb.x);
            const float v1 = fmaf(a1, inv, q01.y + cb.y);
            const float v2 = fmaf(a2, inv, q23.x + cb.z);
            const float v3 = fmaf(a3, inv, q23.y + cb.w);
            uint2 ow;
            ow.x = __builtin_bit_cast(unsigned, __floats2half2_rn(v0, v1));
            ow.y = __builtin_bit_cast(unsigned, __floats2half2_rn(v2, v3));
            if (k < 4) *(uint2*)(g + (size_t)node * 16 + 4 * k) = ow;
            else       *(uint2*)(r + (size_t)node * 16 + 4 * (k - 4)) = ow;
        }
    }
}

// layer 2: 32 lanes per node = 4 edge-slots x 8 dword-lanes (2 fp16 feats per lane)
__global__ __launch_bounds__(256) void agg2_csr(const int* __restrict__ rowptr,
    const int* __restrict__ cols, const __half* __restrict__ g,
    const __half* __restrict__ r, const float* __restrict__ b2,
    __half* __restrict__ h2)
{
    const int node = blockIdx.x * 8 + (threadIdx.x >> 5);
    if (node >= NN) return;
    const int lane = threadIdx.x & 31;
    const int es = lane >> 3;
    const int k  = lane & 7;
    const int beg = rowptr[node], end = rowptr[node + 1];
    const unsigned* g32 = (const unsigned*)g;
    float a0 = 0.f, a1 = 0.f;
#pragma unroll 2
    for (int j = beg; j < end; j += 4) {
        const int jj = j + es;
        const int s = cols[(jj < end) ? jj : (end - 1)];
        const float m = (jj < end) ? 1.0f : 0.0f;
        const float2 v = unpackh2(g32[(size_t)s * 8 + k]);
        a0 = fmaf(v.x, m, a0);
        a1 = fmaf(v.y, m, a1);
    }
    a0 += __shfl_xor(a0, 8, 64);  a0 += __shfl_xor(a0, 16, 64);
    a1 += __shfl_xor(a1, 8, 64);  a1 += __shfl_xor(a1, 16, 64);
    if (es == 0) {
        const float dg = (float)(end - beg);
        const float inv = 1.0f / fmaxf(dg, 1.0f);
        const float2 rv = unpackh2(((const unsigned*)r)[(size_t)node * 8 + k]);
        const float2 bb = *(const float2*)(b2 + 2 * k);
        const float v0 = fmaf(a0, inv, rv.x + bb.x);
        const float v1 = fmaf(a1, inv, rv.y + bb.y);
        ((unsigned*)h2)[(size_t)node * 8 + k] =
            __builtin_bit_cast(unsigned, __floats2half2_rn(v0, v1));
    }
}

// ---- out = sigmoid( sum_k h2[s][k]*h2[d][k]*v[k] + c )
__global__ __launch_bounds__(256) void edge_mlp(const int* __restrict__ src,
    const int* __restrict__ dst, const __half* __restrict__ h2,
    const float* __restrict__ cbuf, float* __restrict__ out)
{
    __shared__ float sv[17];
    if (threadIdx.x < 16) sv[threadIdx.x] = cbuf[32 + threadIdx.x];
    if (threadIdx.x == 16) sv[16] = cbuf[48];
    __syncthreads();
    const int e = blockIdx.x * 256 + threadIdx.x;
    if (e >= NE) return;
    const int s = src[e], d = dst[e];
    const uint4* hs = (const uint4*)(h2 + (size_t)s * 16);
    const uint4* hd = (const uint4*)(h2 + (size_t)d * 16);
    float acc = sv[16];
    const uint4 a0 = hs[0], a1 = hs[1];
    const uint4 b0 = hd[0], b1 = hd[1];
    const unsigned aw[8] = {a0.x, a0.y, a0.z, a0.w, a1.x, a1.y, a1.z, a1.w};
    const unsigned bw[8] = {b0.x, b0.y, b0.z, b0.w, b1.x, b1.y, b1.z, b1.w};
#pragma unroll
    for (int qq = 0; qq < 8; ++qq) {
        const float2 a = unpackh2(aw[qq]);
        const float2 b = unpackh2(bw[qq]);
        acc = fmaf(a.x * b.x, sv[qq * 2 + 0], acc);
        acc = fmaf(a.y * b.y, sv[qq * 2 + 1], acc);
    }
    out[e] = 1.0f / (1.0f + __expf(-acc));
}

extern "C" void kernel_launch(void* const* d_in, const int* in_sizes, int n_in,
                              void* d_out, int out_size, void* d_ws, size_t ws_size,
                              hipStream_t stream)
{
    const float* x    = (const float*)d_in[0];
    const int*   ei   = (const int*)d_in[1];
    const float* w1l  = (const float*)d_in[2];
    const float* w1r  = (const float*)d_in[3];
    const float* b1   = (const float*)d_in[4];
    const float* w2l  = (const float*)d_in[5];
    const float* w2r  = (const float*)d_in[6];
    const float* b2   = (const float*)d_in[7];
    const float* fc1w = (const float*)d_in[8];
    const float* fc1b = (const float*)d_in[9];
    const float* fc2w = (const float*)d_in[10];
    const float* fc2b = (const float*)d_in[11];
    float* out = (float*)d_out;

    const int* src = ei;
    const int* dst = ei + NE;

    // workspace layout (int units)
    int* W = (int*)d_ws;
    size_t o = 0;
#define ALIGN16() o = (o + 15) & ~(size_t)15
    int* mat    = W + o; o += (size_t)NB2 * ABLK; ALIGN16();
    int* bbase  = W + o; o += NB2 + 1;           ALIGN16();
    int* rowptr = W + o; o += NN + 1;            ALIGN16();
    unsigned* part = (unsigned*)(W + o); o += NE; ALIGN16();
    int* cols   = W + o; o += NE;                ALIGN16();
    unsigned short* ATh = (unsigned short*)(W + o); o += 4096; ALIGN16();
    unsigned short* ATl = (unsigned short*)(W + o); o += 4096; ALIGN16();
    float* cbuf = (float*)(W + o); o += 64;      ALIGN16();
    signed char* p8 = (signed char*)(W + o); o += (size_t)NN * 8;  ALIGN16();
    float* pscale   = (float*)(W + o); o += NN;  ALIGN16();
    __half* qh  = (__half*)(W + o); o += (size_t)NN * 16; ALIGN16();
    __half* g   = (__half*)(W + o); o += (size_t)NN * 8;  ALIGN16();
    __half* r   = (__half*)(W + o); o += (size_t)NN * 8;  ALIGN16();
    __half* h2  = (__half*)(W + o); o += (size_t)NN * 8;  ALIGN16();

    precomp<<<129, 64, 0, stream>>>(w1l, w1r, w2l, w2r, b1, fc1w, fc1b, fc2w, fc2b,
                                    ATh, ATl, cbuf);

    // bucket partition
    partA_count<<<ABLK, 256, 0, stream>>>(dst, mat);
    scan_all<<<1, 512, 0, stream>>>(mat, bbase);
    partA_scatter<<<ABLK, 256, 0, stream>>>(src, dst, mat, bbase, part);

    // dense projection (MFMA, int8 payload epilogue)
    gemm_mfma<<<(NN + 63) / 64, 256, 0, stream>>>(x, ATh, ATl, p8, pscale, qh);

    // fused CSR-build + layer-1 aggregation (also emits rowptr/cols for agg2)
    buildagg1<<<NB2, 512, 0, stream>>>(part, bbase, p8, pscale, qh, cbuf,
                                       rowptr, cols, g, r);

    // layer-2 aggregation
    agg2_csr<<<(NN + 7) / 8, 256, 0, stream>>>(rowptr, cols, g, r, b2, h2);

    // head
    edge_mlp<<<NE / 256, 256, 0, stream>>>(src, dst, h2, cbuf, out);
}

// Round 12
// 155.266 us; speedup vs baseline: 1.1479x; 1.1479x over previous
//
#include <hip/hip_runtime.h>
#include <hip/hip_fp16.h>
#include <math.h>

#define NN 100000
#define NE 1600000

#define BSH  9          // bucket = dst >> 9
#define BKN  512        // nodes per bucket
#define NB   196        // ceil(NN/512)
#define ABLK 128        // partition blocks
#define EPB  ((NE + ABLK - 1) / ABLK)   // 12500 edges per partition block

typedef __attribute__((ext_vector_type(8))) short bf16x8;
typedef __attribute__((ext_vector_type(4))) float f32x4;

__device__ __forceinline__ unsigned short f2bf(float f) {
    unsigned u = __builtin_bit_cast(unsigned, f);
    u += 0x7fffu + ((u >> 16) & 1u);           // RNE
    return (unsigned short)(u >> 16);
}
__device__ __forceinline__ float bf2f(unsigned short h) {
    unsigned u = ((unsigned)h) << 16;
    return __builtin_bit_cast(float, u);
}
__device__ __forceinline__ float2 unpackh2(unsigned w) {
    const __half2 h = __builtin_bit_cast(__half2, w);
    return __half22float2(h);
}

// ---- fused precomp: blocks 0..127 -> ATh/ATl (transposed bf16 hi/lo of A);
//      block 128 -> cbuf [0:16)=b1@w2l [16:32)=b1@w2r [32:48)=fc1w@fc2w [48]=c
__global__ __launch_bounds__(64) void precomp(const float* __restrict__ w1l,
    const float* __restrict__ w1r, const float* __restrict__ w2l,
    const float* __restrict__ w2r, const float* __restrict__ b1,
    const float* __restrict__ fc1w, const float* __restrict__ fc1b,
    const float* __restrict__ fc2w, const float* __restrict__ fc2b,
    unsigned short* __restrict__ ATh, unsigned short* __restrict__ ATl,
    float* __restrict__ cbuf)
{
    const int j = threadIdx.x;
    if (blockIdx.x == 128) {
        if (j < 16) {
            float a = 0.f;
            for (int m = 0; m < 64; ++m) a = fmaf(b1[m], w2l[m * 16 + j], a);
            cbuf[j] = a;
        } else if (j < 32) {
            const int jj = j - 16;
            float a = 0.f;
            for (int m = 0; m < 64; ++m) a = fmaf(b1[m], w2r[m * 16 + jj], a);
            cbuf[j] = a;
        } else if (j < 48) {
            const int k = j - 32;
            float a = 0.f;
            for (int m = 0; m < 8; ++m) a = fmaf(fc1w[k * 8 + m], fc2w[m], a);
            cbuf[j] = a;
        } else if (j == 48) {
            float a = fc2b[0];
            for (int m = 0; m < 8; ++m) a = fmaf(fc1b[m], fc2w[m], a);
            cbuf[48] = a;
        }
        return;
    }
    __shared__ float sl[64], sr[64];
    const int k = blockIdx.x;     // input feature 0..127
    sl[j] = w1l[k * 64 + j];
    sr[j] = w1r[k * 64 + j];
    __syncthreads();
    const int sel = j >> 4, jj = j & 15;
    const float* row = (sel < 2) ? sl : sr;
    const float* w2  = (sel & 1) ? w2r : w2l;
    float acc = 0.f;
#pragma unroll
    for (int m = 0; m < 64; ++m) acc = fmaf(row[m], w2[m * 16 + jj], acc);
    const unsigned short h = f2bf(acc);
    ATh[j * 128 + k] = h;                       // transposed: [col][k]
    ATl[j * 128 + k] = f2bf(acc - bf2f(h));
}

// ---- MFMA GEMM: y = x @ A (bf16 3-term split).
//      p (cols 0..31) -> int8 + per-row scale;  q (cols 32..63) -> fp16
#define LDST 136
__global__ __launch_bounds__(256) void gemm_mfma(const float* __restrict__ x,
    const unsigned short* __restrict__ ATh, const unsigned short* __restrict__ ATl,
    signed char* __restrict__ p8, float* __restrict__ pscale,
    __half* __restrict__ qh)
{
    __shared__ unsigned short sAh[64 * LDST];
    __shared__ unsigned short sAl[64 * LDST];
    const int tid = threadIdx.x;
    for (int i = tid; i < 1024; i += 256) {
        const int row = i >> 4, ch = i & 15;
        const uint4 vh = *(const uint4*)(ATh + row * 128 + ch * 8);
        const uint4 vl = *(const uint4*)(ATl + row * 128 + ch * 8);
        *(uint4*)(sAh + row * LDST + ch * 8) = vh;
        *(uint4*)(sAl + row * LDST + ch * 8) = vl;
    }
    __syncthreads();

    const int wave = tid >> 6;
    const int lane = tid & 63;
    const int lr = lane & 15;
    const int lg = lane >> 4;

    bf16x8 bh[4][4], bl[4][4];
#pragma unroll
    for (int ct = 0; ct < 4; ++ct) {
        const int col = ct * 16 + lr;
#pragma unroll
        for (int ks = 0; ks < 4; ++ks) {
            const int k0 = ks * 32 + lg * 8;
            bh[ct][ks] = *(const bf16x8*)(sAh + col * LDST + k0);
            bl[ct][ks] = *(const bf16x8*)(sAl + col * LDST + k0);
        }
    }

    const int tilebase = blockIdx.x * 64;
    const int xrowidx = tilebase + wave * 16 + lr;
    const float* xrow = x + (size_t)(xrowidx < NN ? xrowidx : NN - 1) * 128;

    f32x4 acc[4] = {f32x4{0,0,0,0}, f32x4{0,0,0,0}, f32x4{0,0,0,0}, f32x4{0,0,0,0}};
#pragma unroll
    for (int ks = 0; ks < 4; ++ks) {
        const int k0 = ks * 32 + lg * 8;
        const float4 v0 = *(const float4*)(xrow + k0);
        const float4 v1 = *(const float4*)(xrow + k0 + 4);
        const float vv[8] = {v0.x, v0.y, v0.z, v0.w, v1.x, v1.y, v1.z, v1.w};
        bf16x8 xh, xl;
#pragma unroll
        for (int j = 0; j < 8; ++j) {
            const unsigned short h = f2bf(vv[j]);
            xh[j] = (short)h;
            xl[j] = (short)f2bf(vv[j] - bf2f(h));
        }
#pragma unroll
        for (int ct = 0; ct < 4; ++ct) {
            acc[ct] = __builtin_amdgcn_mfma_f32_16x16x32_bf16(xh, bh[ct][ks], acc[ct], 0, 0, 0);
            acc[ct] = __builtin_amdgcn_mfma_f32_16x16x32_bf16(xh, bl[ct][ks], acc[ct], 0, 0, 0);
            acc[ct] = __builtin_amdgcn_mfma_f32_16x16x32_bf16(xl, bh[ct][ks], acc[ct], 0, 0, 0);
        }
    }

#pragma unroll
    for (int rg = 0; rg < 4; ++rg) {
        float m = fmaxf(fabsf(acc[0][rg]), fabsf(acc[1][rg]));
#pragma unroll
        for (int d = 1; d < 16; d <<= 1) m = fmaxf(m, __shfl_xor(m, d, 64));
        m = fmaxf(m, 1e-20f);
        const float scl = m * (1.0f / 127.0f);
        const float inv = 127.0f / m;
        const int nrow = tilebase + wave * 16 + lg * 4 + rg;
        if (nrow < NN) {
            const int q0 = __float2int_rn(acc[0][rg] * inv);
            const int q1 = __float2int_rn(acc[1][rg] * inv);
            p8[(size_t)nrow * 32 + lr]      = (signed char)q0;
            p8[(size_t)nrow * 32 + 16 + lr] = (signed char)q1;
            if (lr == 0) pscale[nrow] = scl;
            qh[(size_t)nrow * 32 + lr]      = __float2half(acc[2][rg]);
            qh[(size_t)nrow * 32 + 16 + lr] = __float2half(acc[3][rg]);
        }
    }
}

// ============ bucketed CSR build ============
// mat layout: [bucket][ablock]
__global__ __launch_bounds__(256) void partA_count(const int* __restrict__ dst,
    int* __restrict__ mat)
{
    __shared__ int h[NB];
    for (int i = threadIdx.x; i < NB; i += 256) h[i] = 0;
    __syncthreads();
    const int a = blockIdx.x;
    const int beg = a * EPB;
    const int end = (beg + EPB < NE) ? beg + EPB : NE;
    for (int e = beg + threadIdx.x; e < end; e += 256)
        atomicAdd(&h[dst[e] >> BSH], 1);
    __syncthreads();
    for (int i = threadIdx.x; i < NB; i += 256) mat[(size_t)i * ABLK + a] = h[i];
}

__global__ __launch_bounds__(256) void scan_cols(int* __restrict__ mat,
    int* __restrict__ tot)
{
    const int b = blockIdx.x * 256 + threadIdx.x;
    if (b >= NB) return;
    int* col = mat + (size_t)b * ABLK;
    int run = 0;
    for (int a = 0; a < ABLK; ++a) { const int t = col[a]; col[a] = run; run += t; }
    tot[b] = run;
}

__global__ void scan_tot(const int* __restrict__ tot, int* __restrict__ bbase)
{
    if (threadIdx.x == 0) {
        int acc = 0;
        for (int i = 0; i < NB; ++i) { bbase[i] = acc; acc += tot[i]; }
        bbase[NB] = acc;   // == NE
    }
}

// packed entry: (src << BSH) | local_dst
__global__ __launch_bounds__(256) void partA_scatter(const int* __restrict__ src,
    const int* __restrict__ dst, const int* __restrict__ mat,
    const int* __restrict__ bbase, unsigned* __restrict__ part)
{
    __shared__ int cur[NB];
    const int a = blockIdx.x;
    for (int i = threadIdx.x; i < NB; i += 256)
        cur[i] = mat[(size_t)i * ABLK + a] + bbase[i];
    __syncthreads();
    const int beg = a * EPB;
    const int end = (beg + EPB < NE) ? beg + EPB : NE;
    for (int e = beg + threadIdx.x; e < end; e += 256) {
        const int s = src[e], d = dst[e];
        const int pos = atomicAdd(&cur[d >> BSH], 1);
        part[pos] = ((unsigned)s << BSH) | (unsigned)(d & (BKN - 1));
    }
}

__global__ __launch_bounds__(512) void partB_build(const unsigned* __restrict__ part,
    const int* __restrict__ bbase, int* __restrict__ rowptr, int* __restrict__ cols)
{
    __shared__ int h[BKN];
    __shared__ int cur[BKN];
    const int b = blockIdx.x;
    const int beg = bbase[b], end = bbase[b + 1];
    h[threadIdx.x] = 0;
    __syncthreads();
    for (int e = beg + threadIdx.x; e < end; e += 512)
        atomicAdd(&h[part[e] & (BKN - 1u)], 1);
    __syncthreads();
    const int v = h[threadIdx.x];
    for (int off = 1; off < BKN; off <<= 1) {
        const int t = (threadIdx.x >= off) ? h[threadIdx.x - off] : 0;
        __syncthreads();
        h[threadIdx.x] += t;
        __syncthreads();
    }
    const int excl = h[threadIdx.x] - v;
    cur[threadIdx.x] = excl;
    const int node = b * BKN + threadIdx.x;
    if (node < NN) rowptr[node] = beg + excl;
    if (b == NB - 1 && threadIdx.x == 0) rowptr[NN] = NE;
    __syncthreads();
    for (int e = beg + threadIdx.x; e < end; e += 512) {
        const unsigned w = part[e];
        const int pos = atomicAdd(&cur[w & (BKN - 1u)], 1);
        cols[beg + pos] = (int)(w >> BSH);
    }
}

// ============ aggregation via CSR (8 edge-slots x uint2 loads) ============
// layer 1: 32 lanes per node = 8 edge-slots x 4 lanes; lane k loads uint2
// (8 int8 feats) of its edge's p8 row. 16 edge-chains in flight per node.
__global__ __launch_bounds__(256) void agg1_csr(const int* __restrict__ rowptr,
    const int* __restrict__ cols, const signed char* __restrict__ p8,
    const float* __restrict__ pscale, const __half* __restrict__ qh,
    const float* __restrict__ cbuf, __half* __restrict__ g, __half* __restrict__ r)
{
    const int node = blockIdx.x * 8 + (threadIdx.x >> 5);
    if (node >= NN) return;
    const int lane = threadIdx.x & 31;
    const int es = lane >> 2;      // edge slot 0..7
    const int k  = lane & 3;       // uint2 index 0..3 (feats 8k..8k+7)
    const int beg = rowptr[node], end = rowptr[node + 1];
    const uint2* p64 = (const uint2*)p8;
    float a0 = 0.f, a1 = 0.f, a2 = 0.f, a3 = 0.f;
    float a4 = 0.f, a5 = 0.f, a6 = 0.f, a7 = 0.f;
#pragma unroll 2
    for (int j = beg; j < end; j += 8) {
        const int jj = j + es;
        const int s = cols[(jj < end) ? jj : (end - 1)];
        const float scl = (jj < end) ? pscale[s] : 0.f;
        const uint2 w = p64[(size_t)s * 4 + k];
        a0 = fmaf((float)(signed char)(w.x & 0xffu), scl, a0);
        a1 = fmaf((float)(signed char)((w.x >> 8) & 0xffu), scl, a1);
        a2 = fmaf((float)(signed char)((w.x >> 16) & 0xffu), scl, a2);
        a3 = fmaf((float)(signed char)(w.x >> 24), scl, a3);
        a4 = fmaf((float)(signed char)(w.y & 0xffu), scl, a4);
        a5 = fmaf((float)(signed char)((w.y >> 8) & 0xffu), scl, a5);
        a6 = fmaf((float)(signed char)((w.y >> 16) & 0xffu), scl, a6);
        a7 = fmaf((float)(signed char)(w.y >> 24), scl, a7);
    }
#pragma unroll
    for (int d = 4; d <= 16; d <<= 1) {
        a0 += __shfl_xor(a0, d, 64); a1 += __shfl_xor(a1, d, 64);
        a2 += __shfl_xor(a2, d, 64); a3 += __shfl_xor(a3, d, 64);
        a4 += __shfl_xor(a4, d, 64); a5 += __shfl_xor(a5, d, 64);
        a6 += __shfl_xor(a6, d, 64); a7 += __shfl_xor(a7, d, 64);
    }
    if (es == 0) {
        // lane k holds feats 8k..8k+7
        const float dg = (float)(end - beg);
        const float inv = 1.0f / fmaxf(dg, 1.0f);
        const uint4 qw = *(const uint4*)(qh + (size_t)node * 32 + 8 * k);
        const float2 q0 = unpackh2(qw.x), q1 = unpackh2(qw.y);
        const float2 q2 = unpackh2(qw.z), q3 = unpackh2(qw.w);
        const float4 cb0 = *(const float4*)(cbuf + 8 * k);
        const float4 cb1 = *(const float4*)(cbuf + 8 * k + 4);
        const float v0 = fmaf(a0, inv, q0.x + cb0.x);
        const float v1 = fmaf(a1, inv, q0.y + cb0.y);
        const float v2 = fmaf(a2, inv, q1.x + cb0.z);
        const float v3 = fmaf(a3, inv, q1.y + cb0.w);
        const float v4 = fmaf(a4, inv, q2.x + cb1.x);
        const float v5 = fmaf(a5, inv, q2.y + cb1.y);
        const float v6 = fmaf(a6, inv, q3.x + cb1.z);
        const float v7 = fmaf(a7, inv, q3.y + cb1.w);
        uint4 ow;
        ow.x = __builtin_bit_cast(unsigned, __floats2half2_rn(v0, v1));
        ow.y = __builtin_bit_cast(unsigned, __floats2half2_rn(v2, v3));
        ow.z = __builtin_bit_cast(unsigned, __floats2half2_rn(v4, v5));
        ow.w = __builtin_bit_cast(unsigned, __floats2half2_rn(v6, v7));
        if (k < 2) *(uint4*)(g + (size_t)node * 16 + 8 * k) = ow;
        else       *(uint4*)(r + (size_t)node * 16 + 8 * (k - 2)) = ow;
    }
}

// layer 2: 32 lanes per node = 8 edge-slots x 4 lanes; lane k loads uint2
// (4 fp16 feats) of its edge's g row.
__global__ __launch_bounds__(256) void agg2_csr(const int* __restrict__ rowptr,
    const int* __restrict__ cols, const __half* __restrict__ g,
    const __half* __restrict__ r, const float* __restrict__ b2,
    __half* __restrict__ h2)
{
    const int node = blockIdx.x * 8 + (threadIdx.x >> 5);
    if (node >= NN) return;
    const int lane = threadIdx.x & 31;
    const int es = lane >> 2;
    const int k  = lane & 3;       // feats 4k..4k+3
    const int beg = rowptr[node], end = rowptr[node + 1];
    const uint2* g64 = (const uint2*)g;
    float a0 = 0.f, a1 = 0.f, a2 = 0.f, a3 = 0.f;
#pragma unroll 2
    for (int j = beg; j < end; j += 8) {
        const int jj = j + es;
        const int s = cols[(jj < end) ? jj : (end - 1)];
        const float m = (jj < end) ? 1.0f : 0.0f;
        const uint2 w = g64[(size_t)s * 4 + k];
        const float2 v0 = unpackh2(w.x);
        const float2 v1 = unpackh2(w.y);
        a0 = fmaf(v0.x, m, a0);
        a1 = fmaf(v0.y, m, a1);
        a2 = fmaf(v1.x, m, a2);
        a3 = fmaf(v1.y, m, a3);
    }
#pragma unroll
    for (int d = 4; d <= 16; d <<= 1) {
        a0 += __shfl_xor(a0, d, 64); a1 += __shfl_xor(a1, d, 64);
        a2 += __shfl_xor(a2, d, 64); a3 += __shfl_xor(a3, d, 64);
    }
    if (es == 0) {
        const float dg = (float)(end - beg);
        const float inv = 1.0f / fmaxf(dg, 1.0f);
        const uint2 rw = ((const uint2*)r)[(size_t)node * 4 + k];
        const float2 r0 = unpackh2(rw.x), r1 = unpackh2(rw.y);
        const float4 bb = *(const float4*)(b2 + 4 * k);
        const float v0 = fmaf(a0, inv, r0.x + bb.x);
        const float v1 = fmaf(a1, inv, r0.y + bb.y);
        const float v2 = fmaf(a2, inv, r1.x + bb.z);
        const float v3 = fmaf(a3, inv, r1.y + bb.w);
        uint2 ow;
        ow.x = __builtin_bit_cast(unsigned, __floats2half2_rn(v0, v1));
        ow.y = __builtin_bit_cast(unsigned, __floats2half2_rn(v2, v3));
        ((uint2*)h2)[(size_t)node * 4 + k] = ow;
    }
}

// ---- out = sigmoid( sum_k h2[s][k]*h2[d][k]*v[k] + c )
__global__ __launch_bounds__(256) void edge_mlp(const int* __restrict__ src,
    const int* __restrict__ dst, const __half* __restrict__ h2,
    const float* __restrict__ cbuf, float* __restrict__ out)
{
    __shared__ float sv[17];
    if (threadIdx.x < 16) sv[threadIdx.x] = cbuf[32 + threadIdx.x];
    if (threadIdx.x == 16) sv[16] = cbuf[48];
    __syncthreads();
    const int e = blockIdx.x * 256 + threadIdx.x;
    if (e >= NE) return;
    const int s = src[e], d = dst[e];
    const uint4* hs = (const uint4*)(h2 + (size_t)s * 16);
    const uint4* hd = (const uint4*)(h2 + (size_t)d * 16);
    float acc = sv[16];
    const uint4 a0 = hs[0], a1 = hs[1];
    const uint4 b0 = hd[0], b1 = hd[1];
    const unsigned aw[8] = {a0.x, a0.y, a0.z, a0.w, a1.x, a1.y, a1.z, a1.w};
    const unsigned bw[8] = {b0.x, b0.y, b0.z, b0.w, b1.x, b1.y, b1.z, b1.w};
#pragma unroll
    for (int qq = 0; qq < 8; ++qq) {
        const float2 a = unpackh2(aw[qq]);
        const float2 b = unpackh2(bw[qq]);
        acc = fmaf(a.x * b.x, sv[qq * 2 + 0], acc);
        acc = fmaf(a.y * b.y, sv[qq * 2 + 1], acc);
    }
    out[e] = 1.0f / (1.0f + __expf(-acc));
}

extern "C" void kernel_launch(void* const* d_in, const int* in_sizes, int n_in,
                              void* d_out, int out_size, void* d_ws, size_t ws_size,
                              hipStream_t stream)
{
    const float* x    = (const float*)d_in[0];
    const int*   ei   = (const int*)d_in[1];
    const float* w1l  = (const float*)d_in[2];
    const float* w1r  = (const float*)d_in[3];
    const float* b1   = (const float*)d_in[4];
    const float* w2l  = (const float*)d_in[5];
    const float* w2r  = (const float*)d_in[6];
    const float* b2   = (const float*)d_in[7];
    const float* fc1w = (const float*)d_in[8];
    const float* fc1b = (const float*)d_in[9];
    const float* fc2w = (const float*)d_in[10];
    const float* fc2b = (const float*)d_in[11];
    float* out = (float*)d_out;

    const int* src = ei;
    const int* dst = ei + NE;

    // workspace layout (int units)
    int* W = (int*)d_ws;
    size_t o = 0;
#define ALIGN16() o = (o + 15) & ~(size_t)15
    int* mat    = W + o; o += (size_t)NB * ABLK; ALIGN16();
    int* tot    = W + o; o += NB;                ALIGN16();
    int* bbase  = W + o; o += NB + 1;            ALIGN16();
    int* rowptr = W + o; o += NN + 1;            ALIGN16();
    unsigned* part = (unsigned*)(W + o); o += NE; ALIGN16();
    int* cols   = W + o; o += NE;                ALIGN16();
    unsigned short* ATh = (unsigned short*)(W + o); o += 4096; ALIGN16();
    unsigned short* ATl = (unsigned short*)(W + o); o += 4096; ALIGN16();
    float* cbuf = (float*)(W + o); o += 64;      ALIGN16();
    signed char* p8 = (signed char*)(W + o); o += (size_t)NN * 8;  ALIGN16();
    float* pscale   = (float*)(W + o); o += NN;  ALIGN16();
    __half* qh  = (__half*)(W + o); o += (size_t)NN * 16; ALIGN16();
    __half* g   = (__half*)(W + o); o += (size_t)NN * 8;  ALIGN16();
    __half* r   = (__half*)(W + o); o += (size_t)NN * 8;  ALIGN16();
    __half* h2  = (__half*)(W + o); o += (size_t)NN * 8;  ALIGN16();

    precomp<<<129, 64, 0, stream>>>(w1l, w1r, w2l, w2r, b1, fc1w, fc1b, fc2w, fc2b,
                                    ATh, ATl, cbuf);

    // bucketed CSR build (parallel scan)
    partA_count<<<ABLK, 256, 0, stream>>>(dst, mat);
    scan_cols<<<(NB + 255) / 256, 256, 0, stream>>>(mat, tot);
    scan_tot<<<1, 64, 0, stream>>>(tot, bbase);
    partA_scatter<<<ABLK, 256, 0, stream>>>(src, dst, mat, bbase, part);
    partB_build<<<NB, 512, 0, stream>>>(part, bbase, rowptr, cols);

    // dense projection (MFMA, int8 payload epilogue)
    gemm_mfma<<<(NN + 63) / 64, 256, 0, stream>>>(x, ATh, ATl, p8, pscale, qh);

    // aggregations (8 edge-slots, uint2 gathers, 16 chains in flight)
    agg1_csr<<<(NN + 7) / 8, 256, 0, stream>>>(rowptr, cols, p8, pscale, qh, cbuf, g, r);
    agg2_csr<<<(NN + 7) / 8, 256, 0, stream>>>(rowptr, cols, g, r, b2, h2);

    // head
    edge_mlp<<<NE / 256, 256, 0, stream>>>(src, dst, h2, cbuf, out);
}